// Round 1
// baseline (5359.476 us; speedup 1.0000x reference)
//
#include <hip/hip_runtime.h>

#define NB 128      // batch
#define NT 8192     // time steps
#define NS 128      // states
#define NE 6        // alphabet

__global__ void __launch_bounds__(128, 1)
hmm_forward_kernel(const int* __restrict__ obs, const float* __restrict__ I,
                   const float* __restrict__ A, const float* __restrict__ Bm,
                   float* __restrict__ out)
{
    __shared__ float4 alpha4[2][NS / 4];   // double-buffered alpha, 16B-aligned
    __shared__ float  Bmt[NE * NS];        // Bm transposed: Bmt[o*NS + s]
    __shared__ int    obs_s[128];          // 128-step obs chunk
    __shared__ float  red[2];              // per-wave partial sums

    const int tid = threadIdx.x;
    const int b   = blockIdx.x;
    const int* obs_row = obs + b * NT;

    // Each thread holds column A[:, tid] in registers.
    // A[i*NS + tid] is coalesced across tid for each i.
    float acol[NS];
#pragma unroll
    for (int i = 0; i < NS; ++i) acol[i] = A[i * NS + tid];

    // Transpose Bm into LDS: Bmt[o*NS + s] = Bm[s*NE + o]
#pragma unroll
    for (int k = 0; k < NE; ++k) Bmt[k * NS + tid] = Bm[tid * NE + k];

    // first obs chunk [0, 128)
    obs_s[tid] = obs_row[tid];
    __syncthreads();

    int cur = 0;
    // t = 0: alpha = I * em_0 (unnormalized)
    {
        int o0 = obs_s[0];
        ((float*)alpha4[0])[tid] = I[tid] * Bmt[o0 * NS + tid];
    }
    __syncthreads();

    float ll = 0.0f;

    auto do_step = [&](int o) {
        const float4* ab = (const float4*)alpha4[cur];
        float acc0 = 0.f, acc1 = 0.f, acc2 = 0.f, acc3 = 0.f;
#pragma unroll
        for (int q = 0; q < NS / 4; ++q) {
            float4 v = ab[q];                       // wave-uniform -> LDS broadcast
            acc0 = fmaf(v.x, acol[4 * q + 0], acc0);
            acc1 = fmaf(v.y, acol[4 * q + 1], acc1);
            acc2 = fmaf(v.z, acol[4 * q + 2], acc2);
            acc3 = fmaf(v.w, acol[4 * q + 3], acc3);
        }
        float an = ((acc0 + acc1) + (acc2 + acc3)) * Bmt[o * NS + tid];
        ((float*)alpha4[cur ^ 1])[tid] = an;        // lane-consecutive write
        __syncthreads();
        cur ^= 1;
    };

    auto rescale = [&]() {
        float v = ((float*)alpha4[cur])[tid];
        float s = v;
#pragma unroll
        for (int off = 32; off > 0; off >>= 1) s += __shfl_xor(s, off);
        if ((tid & 63) == 0) red[tid >> 6] = s;
        __syncthreads();
        float Z = red[0] + red[1];                  // uniform across block
        ll += logf(Z);
        ((float*)alpha4[cur])[tid] = v * (1.0f / Z);
        __syncthreads();
    };

    // steps t = 1..7, then rescale (captures log(Z0*...*Z7))
#pragma unroll
    for (int j = 1; j < 8; ++j) do_step(obs_s[j]);
    rescale();

    // main loop: groups of 8 steps + rescale; obs chunk reload every 128 steps
    for (int g = 8; g < NT; g += 8) {
        if ((g & 127) == 0) {
            obs_s[tid] = obs_row[g + tid];
            __syncthreads();
        }
#pragma unroll
        for (int j = 0; j < 8; ++j) do_step(obs_s[(g + j) & 127]);
        rescale();
    }

    // ll == sum_t log Z_t (telescoped); identical for all threads
    if (tid == 0) out[b] = ll;
}

extern "C" void kernel_launch(void* const* d_in, const int* in_sizes, int n_in,
                              void* d_out, int out_size, void* d_ws, size_t ws_size,
                              hipStream_t stream) {
    (void)in_sizes; (void)n_in; (void)d_ws; (void)ws_size; (void)out_size;
    const int*   obs = (const int*)d_in[0];
    const float* I   = (const float*)d_in[1];
    const float* A   = (const float*)d_in[2];
    const float* Bm  = (const float*)d_in[3];
    float*       out = (float*)d_out;

    hipLaunchKernelGGL(hmm_forward_kernel, dim3(NB), dim3(128), 0, stream,
                       obs, I, A, Bm, out);
}